// Round 1
// 530.347 us; speedup vs baseline: 1.0374x; 1.0374x over previous
//
#include <hip/hip_runtime.h>
#include <hip/hip_bf16.h>

typedef _Float16 half8 __attribute__((ext_vector_type(8)));
typedef float floatx4 __attribute__((ext_vector_type(4)));

// ---------------------------------------------------------------------------
// Kernel 1: Sinkhorn on the 128x128 matrix, factored form.
// One block, 256 threads (4 waves). Threads 0..127 ("row" waves) each own row
// i of A0 in 128 VGPRs; threads 128..255 ("col" waves) each own column i of
// A0 in 128 VGPRs (filled once via a padded-LDS transpose). A0 is never
// rescaled; we iterate
//   r = 1 / (A0 c)        (row-normalize step, row waves)
//   c = 1 / (A0^T r)      (col-normalize step, col waves)
// 128 floats/thread fits the 256-VGPR architectural file -> no scratch spill
// (the previous version held row AND column per thread = 256 floats, which
// spilled to scratch and made the kernel latency-bound at ~202us).
// Final P[i][j] = r_i * A0[i][j] * c_j, written row-major as f16.
// ---------------------------------------------------------------------------
__global__ __launch_bounds__(256, 1) void sinkhorn128(
    const float* __restrict__ logits, const float* __restrict__ u,
    _Float16* __restrict__ Pout) {
    __shared__ float sA[128 * 129];           // +1 pad: conflict-free transpose
    __shared__ alignas(16) float sR[128];     // r vector (row waves -> col waves)
    __shared__ alignas(16) float sC[128];     // c vector (col waves -> row waves)
    const int t = threadIdx.x;
    const int i = t & 127;
    const bool isRow = (t < 128);             // wave-uniform split (waves 0,1 vs 2,3)

    float a[128];  // row i of A0 (row threads) / column i of A0 (col threads)

    if (isRow) {
        // A0 = exp(clip((logits + gumbel)/T, -10, 10))
        #pragma unroll
        for (int j = 0; j < 128; ++j) {
            float lg = logits[i * 128 + j];
            float uu = u[i * 128 + j];
            float g  = -logf(-logf(uu + 1e-20f) + 1e-20f);  // NOISE_SCALE = 1
            float la = (lg + g) / 3.0f;                      // TEMPERATURE = 3
            la = fminf(10.0f, fmaxf(-10.0f, la));
            float v = expf(la);
            a[j] = v;
            sA[i * 129 + j] = v;
        }
        sC[i] = 1.0f;  // c := ones
    }
    __syncthreads();
    if (!isRow) {
        // column i of A0; lane l reads sA[j*129 + l]: banks (j*129+l)%32 are
        // distinct per lane -> conflict-free. sA is never written again.
        #pragma unroll
        for (int j = 0; j < 128; ++j) a[j] = sA[j * 129 + i];
    }

    float ri = 1.0f;
    for (int it = 0; it < 20; ++it) {
        // --- row phase: ri = 1 / sum_j a[j] * c[j] ---
        if (isRow) {
            float s0 = 0.f, s1 = 0.f, s2 = 0.f, s3 = 0.f;
            #pragma unroll
            for (int j = 0; j < 128; j += 4) {
                float4 c4 = *reinterpret_cast<const float4*>(&sC[j]);
                s0 = fmaf(a[j + 0], c4.x, s0);
                s1 = fmaf(a[j + 1], c4.y, s1);
                s2 = fmaf(a[j + 2], c4.z, s2);
                s3 = fmaf(a[j + 3], c4.w, s3);
            }
            ri = 1.0f / ((s0 + s1) + (s2 + s3));
            sR[i] = ri;   // safe: col waves' sR reads ended before last barrier
        }
        __syncthreads();  // sR visible; row waves done reading sC
        // --- col phase: ci = 1 / sum_j a[j] * r[j] ---
        if (!isRow) {
            float s0 = 0.f, s1 = 0.f, s2 = 0.f, s3 = 0.f;
            #pragma unroll
            for (int j = 0; j < 128; j += 4) {
                float4 r4 = *reinterpret_cast<const float4*>(&sR[j]);
                s0 = fmaf(a[j + 0], r4.x, s0);
                s1 = fmaf(a[j + 1], r4.y, s1);
                s2 = fmaf(a[j + 2], r4.z, s2);
                s3 = fmaf(a[j + 3], r4.w, s3);
            }
            float ci = 1.0f / ((s0 + s1) + (s2 + s3));
            sC[i] = ci;   // safe: row waves done reading sC since the barrier
        }
        __syncthreads();  // sC visible for next iteration / epilogue
    }

    // P row i = ri * a[j] * c[j], cast to f16, row-major (this IS B^T's row n)
    if (isRow) {
        #pragma unroll
        for (int j = 0; j < 128; j += 2) {
            union { _Float16 h[2]; unsigned int w; } pk;
            pk.h[0] = (_Float16)(ri * a[j + 0] * sC[j + 0]);
            pk.h[1] = (_Float16)(ri * a[j + 1] * sC[j + 1]);
            reinterpret_cast<unsigned int*>(Pout)[(i * 128 + j) >> 1] = pk.w;
        }
    }
}

// ---------------------------------------------------------------------------
// Kernel 2: out = x @ P.T, streaming MFMA, no LDS.  (unchanged this round)
// Each wave keeps ALL B fragments (P.T, f16) in 128 VGPRs and processes 16
// blocks of 16 rows. x is split into f16 hi + f16 lo (2 MFMAs/accumulate) so
// the f32->f16 input rounding error is ~2^-22 on the x side.
// A-frag: lane holds x[m0 + (l&15)][ks*32 + (l>>4)*8 + j]  (8 contiguous f32)
// B-frag: lane holds P[nt*16 + (l&15)][ks*32 + (l>>4)*8 + j] (8 contiguous f16)
// C/D:    lane l holds C[(l>>4)*4 + rr][l&15]
// ---------------------------------------------------------------------------
__global__ __launch_bounds__(256, 2) void streamMatmul(
    const float* __restrict__ x, const _Float16* __restrict__ P,
    float* __restrict__ out) {
    const int lane = threadIdx.x & 63;
    const int wv   = threadIdx.x >> 6;
    const int gw   = blockIdx.x * 4 + wv;   // 0..2047
    const int r    = lane & 15;
    const int q    = lane >> 4;

    // Load all B fragments once: 4 k-steps x 8 n-tiles x 8 f16 = 128 VGPRs
    half8 Bf[4][8];
    #pragma unroll
    for (int ks = 0; ks < 4; ++ks)
        #pragma unroll
        for (int nt = 0; nt < 8; ++nt)
            Bf[ks][nt] = *reinterpret_cast<const half8*>(
                P + (nt * 16 + r) * 128 + ks * 32 + q * 8);

    const long baseRow = (long)gw * 256;    // 2048 waves x 256 rows = 524288
    for (int t = 0; t < 16; ++t) {
        const long m0 = baseRow + t * 16;
        const float* xp = x + (m0 + r) * 128 + q * 8;

        // Issue all x loads (8 x dwordx4, nontemporal) before converting
        floatx4 xa[4][2];
        #pragma unroll
        for (int ks = 0; ks < 4; ++ks) {
            xa[ks][0] = __builtin_nontemporal_load(
                reinterpret_cast<const floatx4*>(xp + ks * 32));
            xa[ks][1] = __builtin_nontemporal_load(
                reinterpret_cast<const floatx4*>(xp + ks * 32 + 4));
        }

        floatx4 acc[8];
        #pragma unroll
        for (int nt = 0; nt < 8; ++nt) acc[nt] = (floatx4){0.f, 0.f, 0.f, 0.f};

        #pragma unroll
        for (int ks = 0; ks < 4; ++ks) {
            half8 ahi, alo;
            #pragma unroll
            for (int jj = 0; jj < 8; ++jj) {
                float f = (jj < 4) ? xa[ks][0][jj] : xa[ks][1][jj - 4];
                _Float16 h = (_Float16)f;
                ahi[jj] = h;
                alo[jj] = (_Float16)(f - (float)h);
            }
            #pragma unroll
            for (int nt = 0; nt < 8; ++nt) {
                acc[nt] = __builtin_amdgcn_mfma_f32_16x16x32_f16(
                    ahi, Bf[ks][nt], acc[nt], 0, 0, 0);
                acc[nt] = __builtin_amdgcn_mfma_f32_16x16x32_f16(
                    alo, Bf[ks][nt], acc[nt], 0, 0, 0);
            }
        }

        // Store: lane l owns rows (q*4 + rr), col (nt*16 + r).
        // 16 lanes x 4B = 64B contiguous per row per instr -> coalesced 64B segs.
        float* op = out + (m0 + q * 4) * 128 + r;
        #pragma unroll
        for (int nt = 0; nt < 8; ++nt)
            #pragma unroll
            for (int rr = 0; rr < 4; ++rr)
                __builtin_nontemporal_store(acc[nt][rr], op + rr * 128 + nt * 16);
    }
}

extern "C" void kernel_launch(void* const* d_in, const int* in_sizes, int n_in,
                              void* d_out, int out_size, void* d_ws, size_t ws_size,
                              hipStream_t stream) {
    (void)in_sizes; (void)n_in; (void)out_size; (void)ws_size;
    const float* x      = (const float*)d_in[0];  // [524288,128] f32
    const float* logits = (const float*)d_in[1];  // [128,128] f32
    const float* u      = (const float*)d_in[2];  // [128,128] f32
    float* out          = (float*)d_out;          // [524288,128] f32
    _Float16* P         = (_Float16*)d_ws;        // [128,128] f16 scratch

    sinkhorn128<<<1, 256, 0, stream>>>(logits, u, P);
    streamMatmul<<<512, 256, 0, stream>>>(x, P, out);
}

// Round 2
// 494.050 us; speedup vs baseline: 1.1136x; 1.0735x over previous
//
#include <hip/hip_runtime.h>
#include <hip/hip_bf16.h>

typedef _Float16 half8 __attribute__((ext_vector_type(8)));
typedef float floatx4 __attribute__((ext_vector_type(4)));

// ---------------------------------------------------------------------------
// Kernel 1: Sinkhorn on the 128x128 matrix, factored form.
// One block, 1024 threads (16 waves). Threads 0..511: (row i = t>>2,
// quarter q = t&3) own a 32-float slice of row i of A0 in regs. Threads
// 512..1023: same for column i. Partial dot products are combined across the
// 4 owner threads with two __shfl_xor (4-aligned groups, always same wave).
// 32 floats/thread is far below the spill threshold (the 128-float version
// still ran ~180us: spill/latency-bound). Init is lane-coalesced and the
// log/exp transcendentals are spread over 1024 threads instead of 128.
//   r = 1 / (A0 c),  c = 1 / (A0^T r),  20 iters;  P = diag(r) A0 diag(c).
// ---------------------------------------------------------------------------
__global__ __launch_bounds__(1024, 1) void sinkhorn128(
    const float* __restrict__ logits, const float* __restrict__ u,
    _Float16* __restrict__ Pout) {
    __shared__ float sA[128 * 129];           // +1 pad: conflict-free transpose
    __shared__ alignas(16) float sR[128];
    __shared__ alignas(16) float sC[128];
    const int t = threadIdx.x;

    // Build A0 = exp(clip((logits+gumbel)/T,-10,10)), 16 elements per thread,
    // consecutive lanes -> consecutive addresses (coalesced global loads).
    #pragma unroll
    for (int k = 0; k < 16; ++k) {
        int e = t + (k << 10);                // e in [0,16384)
        float lg = logits[e];
        float uu = u[e];
        float g  = -logf(-logf(uu + 1e-20f) + 1e-20f);  // NOISE_SCALE = 1
        float la = (lg + g) * (1.0f / 3.0f);             // TEMPERATURE = 3
        la = fminf(10.0f, fmaxf(-10.0f, la));
        sA[(e >> 7) * 129 + (e & 127)] = expf(la);
    }
    if (t < 128) sC[t] = 1.0f;
    __syncthreads();

    const bool isRow = (t < 512);             // wave-uniform (waves 0-7 vs 8-15)
    const int i = (t & 511) >> 2;             // row / column index
    const int q = t & 3;                      // quarter of the 128-dot

    float a[32];                              // 32-elem slice, lives in VGPRs
    if (isRow) {
        #pragma unroll
        for (int j = 0; j < 32; ++j) a[j] = sA[i * 129 + q * 32 + j];
    } else {
        #pragma unroll
        for (int j = 0; j < 32; ++j) a[j] = sA[(q * 32 + j) * 129 + i];
    }

    float ri = 1.0f;
    for (int it = 0; it < 20; ++it) {
        if (isRow) {                          // ri = 1 / sum_j A[i][j] c[j]
            float s0 = 0.f, s1 = 0.f, s2 = 0.f, s3 = 0.f;
            #pragma unroll
            for (int j = 0; j < 32; j += 4) {
                float4 c4 = *reinterpret_cast<const float4*>(&sC[q * 32 + j]);
                s0 = fmaf(a[j + 0], c4.x, s0);
                s1 = fmaf(a[j + 1], c4.y, s1);
                s2 = fmaf(a[j + 2], c4.z, s2);
                s3 = fmaf(a[j + 3], c4.w, s3);
            }
            float p = (s0 + s1) + (s2 + s3);
            p += __shfl_xor(p, 1);            // combine the 4 quarter-partials
            p += __shfl_xor(p, 2);
            ri = 1.0f / p;
            if (q == 0) sR[i] = ri;
        }
        __syncthreads();                      // sR visible; rows done with sC
        if (!isRow) {                         // cj = 1 / sum_i A[i][j] r[i]
            float s0 = 0.f, s1 = 0.f, s2 = 0.f, s3 = 0.f;
            #pragma unroll
            for (int j = 0; j < 32; j += 4) {
                float4 r4 = *reinterpret_cast<const float4*>(&sR[q * 32 + j]);
                s0 = fmaf(a[j + 0], r4.x, s0);
                s1 = fmaf(a[j + 1], r4.y, s1);
                s2 = fmaf(a[j + 2], r4.z, s2);
                s3 = fmaf(a[j + 3], r4.w, s3);
            }
            float p = (s0 + s1) + (s2 + s3);
            p += __shfl_xor(p, 1);
            p += __shfl_xor(p, 2);
            if (q == 0) sC[i] = 1.0f / p;
        }
        __syncthreads();                      // sC visible for next iter / epilogue
    }

    // P[i][q*32+j] = ri * a[j] * c[q*32+j], f16, row-major.
    if (isRow) {
        #pragma unroll
        for (int j = 0; j < 32; j += 2) {
            union { _Float16 h[2]; unsigned int w; } pk;
            pk.h[0] = (_Float16)(ri * a[j + 0] * sC[q * 32 + j + 0]);
            pk.h[1] = (_Float16)(ri * a[j + 1] * sC[q * 32 + j + 1]);
            reinterpret_cast<unsigned int*>(Pout)[(i * 128 + q * 32 + j) >> 1] = pk.w;
        }
    }
}

// ---------------------------------------------------------------------------
// Kernel 2: out = x @ P.T, streaming MFMA, no LDS.
// CHANGES vs previous round:
//  * __launch_bounds__(256, 1): the old (256,2) capped VGPRs at 128 while the
//    kernel needs ~220 (Bf alone is 128) -> the whole hot loop was spilling
//    to scratch. Now everything fits in the 256-VGPR file (1 wave/SIMD; ILP
//    provides the in-flight bytes: 4 waves x 8KB per CU covers HBM latency).
//  * x loads are plain cached loads (each 64B line is split across two load
//    instructions; nontemporal defeated the L1 merge -> ~2x overfetch).
//  * software pipeline: tile t+1's x is prefetched right after tile t's xa
//    registers are consumed by the f16 hi/lo conversion.
// A-frag: lane holds x[m0 + (l&15)][ks*32 + (l>>4)*8 + j]  (8 contiguous f32)
// B-frag: lane holds P[nt*16 + (l&15)][ks*32 + (l>>4)*8 + j] (8 contiguous f16)
// C/D:    lane l holds C[(l>>4)*4 + rr][l&15]
// ---------------------------------------------------------------------------
__global__ __launch_bounds__(256, 1) void streamMatmul(
    const float* __restrict__ x, const _Float16* __restrict__ P,
    float* __restrict__ out) {
    const int lane = threadIdx.x & 63;
    const int wv   = threadIdx.x >> 6;
    const int gw   = blockIdx.x * 4 + wv;   // 0..2047
    const int r    = lane & 15;
    const int q    = lane >> 4;

    // All B fragments resident: 4 k-steps x 8 n-tiles x 8 f16 = 128 VGPRs
    half8 Bf[4][8];
    #pragma unroll
    for (int ks = 0; ks < 4; ++ks)
        #pragma unroll
        for (int nt = 0; nt < 8; ++nt)
            Bf[ks][nt] = *reinterpret_cast<const half8*>(
                P + (nt * 16 + r) * 128 + ks * 32 + q * 8);

    const long baseRow = (long)gw * 256;    // 2048 waves x 256 rows = 524288
    const float* xp0 = x + (baseRow + r) * 128 + q * 8;

    // Prologue: load tile 0
    floatx4 xa[4][2];
    #pragma unroll
    for (int ks = 0; ks < 4; ++ks) {
        xa[ks][0] = *reinterpret_cast<const floatx4*>(xp0 + ks * 32);
        xa[ks][1] = *reinterpret_cast<const floatx4*>(xp0 + ks * 32 + 4);
    }

    for (int t = 0; t < 16; ++t) {
        // Convert current tile to f16 hi + lo (frees xa)
        half8 ah[4], al[4];
        #pragma unroll
        for (int ks = 0; ks < 4; ++ks)
            #pragma unroll
            for (int jj = 0; jj < 8; ++jj) {
                float f = (jj < 4) ? xa[ks][0][jj] : xa[ks][1][jj - 4];
                _Float16 h = (_Float16)f;
                ah[ks][jj] = h;
                al[ks][jj] = (_Float16)(f - (float)h);
            }

        // Prefetch next tile while the MFMA cluster runs
        if (t < 15) {
            const float* xp = xp0 + (t + 1) * 16 * 128;
            #pragma unroll
            for (int ks = 0; ks < 4; ++ks) {
                xa[ks][0] = *reinterpret_cast<const floatx4*>(xp + ks * 32);
                xa[ks][1] = *reinterpret_cast<const floatx4*>(xp + ks * 32 + 4);
            }
        }

        floatx4 acc[8];
        #pragma unroll
        for (int nt = 0; nt < 8; ++nt) acc[nt] = (floatx4){0.f, 0.f, 0.f, 0.f};

        #pragma unroll
        for (int ks = 0; ks < 4; ++ks)
            #pragma unroll
            for (int nt = 0; nt < 8; ++nt) {
                acc[nt] = __builtin_amdgcn_mfma_f32_16x16x32_f16(
                    ah[ks], Bf[ks][nt], acc[nt], 0, 0, 0);
                acc[nt] = __builtin_amdgcn_mfma_f32_16x16x32_f16(
                    al[ks], Bf[ks][nt], acc[nt], 0, 0, 0);
            }

        // Store: lane l owns rows (q*4 + rr), col (nt*16 + r).
        // 16 lanes x 4B = 64B contiguous per instr -> full-line NT stores.
        const long m0 = baseRow + t * 16;
        float* op = out + (m0 + q * 4) * 128 + r;
        #pragma unroll
        for (int nt = 0; nt < 8; ++nt)
            #pragma unroll
            for (int rr = 0; rr < 4; ++rr)
                __builtin_nontemporal_store(acc[nt][rr], op + rr * 128 + nt * 16);
    }
}

extern "C" void kernel_launch(void* const* d_in, const int* in_sizes, int n_in,
                              void* d_out, int out_size, void* d_ws, size_t ws_size,
                              hipStream_t stream) {
    (void)in_sizes; (void)n_in; (void)out_size; (void)ws_size;
    const float* x      = (const float*)d_in[0];  // [524288,128] f32
    const float* logits = (const float*)d_in[1];  // [128,128] f32
    const float* u      = (const float*)d_in[2];  // [128,128] f32
    float* out          = (float*)d_out;          // [524288,128] f32
    _Float16* P         = (_Float16*)d_ws;        // [128,128] f16 scratch

    sinkhorn128<<<1, 1024, 0, stream>>>(logits, u, P);
    streamMatmul<<<512, 256, 0, stream>>>(x, P, out);
}